// Round 11
// baseline (242.974 us; speedup 1.0000x reference)
//
#include <hip/hip_runtime.h>

typedef __attribute__((ext_vector_type(8))) short short8;
typedef __attribute__((ext_vector_type(4))) float f32x4;
typedef __attribute__((ext_vector_type(16))) float f32x16;
typedef __attribute__((ext_vector_type(4))) unsigned int u32x4;

#define B_ 2
#define N_ 2048
#define C_ 1024
#define H_ 16
#define SCALE_ 0.03125f

__device__ inline unsigned short f2bf(float f) {
    unsigned int u = __float_as_uint(f);
    return (unsigned short)((u + 0x7fffu + ((u >> 16) & 1u)) >> 16);
}

__device__ inline f32x4 mfma16(short8 a, short8 b, f32x4 c) {
    return __builtin_amdgcn_mfma_f32_16x16x32_bf16(a, b, c, 0, 0, 0);
}
__device__ inline f32x16 mfma32(short8 a, short8 b, f32x16 c) {
    return __builtin_amdgcn_mfma_f32_32x32x16_bf16(a, b, c, 0, 0, 0);
}

#define GLOAD_LDS16(g, l) __builtin_amdgcn_global_load_lds( \
    (const __attribute__((address_space(1))) void*)(g),     \
    (__attribute__((address_space(3))) void*)(l), 16, 0, 0)

#define CVTPK(d, x, y) asm("v_cvt_pk_bf16_f32 %0, %1, %2" : "=v"(d) : "v"(x), "v"(y))
#define PLSWAP(a, b) asm volatile("v_permlane32_swap_b32 %0, %1" : "+v"(a), "+v"(b))

// ---------------- fused fp32 -> bf16 convert ----------------
__global__ void cvt_all(const float* __restrict__ x, const float* __restrict__ wq,
                        const float* __restrict__ wp, unsigned short* __restrict__ xb,
                        unsigned short* __restrict__ wqb, unsigned short* __restrict__ wpb) {
    int i = blockIdx.x * blockDim.x + threadIdx.x;
    const int n1 = 4096 * 1024 / 4, n2 = 3072 * 1024 / 4;
    const float* src; unsigned short* dst; int j;
    if (i < n1)            { src = x;  dst = xb;  j = i; }
    else if (i < n1 + n2)  { src = wq; dst = wqb; j = i - n1; }
    else                   { src = wp; dst = wpb; j = i - n1 - n2; }
    float4 v = *(const float4*)(src + (size_t)j * 4);
    ushort4 o;
    o.x = f2bf(v.x); o.y = f2bf(v.y); o.z = f2bf(v.z); o.w = f2bf(v.w);
    *(ushort4*)(dst + (size_t)j * 4) = o;
}

// ---------------- bf16 B^T GEMM, BMx128 tile, BK=64 (unchanged) ----------------
template<int BF16_OUT, int BM>
__global__ __launch_bounds__(256, 3)
void gemm_bt(const unsigned short* __restrict__ A, const unsigned short* __restrict__ Bm,
             unsigned short* __restrict__ Cb, float* __restrict__ Cf,
             const float* __restrict__ bias, int M, int N, int K,
             int xcd_cols, int bxr) {
    constexpr int AI = BM / 32;
    __shared__ unsigned short lA[BM * 64];
    __shared__ unsigned short lB[128 * 64];
    const int tid = threadIdx.x;
    const int lane = tid & 63, wave = tid >> 6;
    const int lm = lane & 15, g = lane >> 4;
    const int flat = blockIdx.x, per = gridDim.x >> 3;
    const int xcd = flat & 7, fl = flat >> 3;
    const int rpr = per / bxr;
    const int by = (xcd / xcd_cols) * rpr + fl / bxr;
    const int bx = (xcd % xcd_cols) * bxr + fl % bxr;
    const int m0 = by * BM, n0 = bx * 128;
    const int wr = wave >> 1, wc = wave & 1;

    f32x4 acc[AI][4];
    f32x4 zero = {0.f, 0.f, 0.f, 0.f};
#pragma unroll
    for (int i = 0; i < AI; ++i)
#pragma unroll
        for (int j = 0; j < 4; ++j) acc[i][j] = zero;

    const int sRow = lane >> 3;
    const int sCol = (lane & 7) * 8;

    for (int k0 = 0; k0 < K; k0 += 64) {
#pragma unroll
        for (int t = 0; t < AI; ++t) {
            int inst = wave * AI + t;
            int r = inst * 8 + sRow;
            GLOAD_LDS16(A + (size_t)(m0 + r) * K + k0 + sCol, lA + inst * 512);
        }
#pragma unroll
        for (int t = 0; t < 4; ++t) {
            int inst = wave * 4 + t;
            int r = inst * 8 + sRow;
            GLOAD_LDS16(Bm + (size_t)(n0 + r) * K + k0 + sCol, lB + inst * 512);
        }
        __syncthreads();
#pragma unroll
        for (int kk = 0; kk < 2; ++kk) {
            short8 af[AI], bfv[4];
#pragma unroll
            for (int i = 0; i < AI; ++i)
                af[i] = *(const short8*)&lA[(wr * (BM / 2) + i * 16 + lm) * 64 + kk * 32 + g * 8];
#pragma unroll
            for (int j = 0; j < 4; ++j)
                bfv[j] = *(const short8*)&lB[(wc * 64 + j * 16 + lm) * 64 + kk * 32 + g * 8];
#pragma unroll
            for (int i = 0; i < AI; ++i)
#pragma unroll
                for (int j = 0; j < 4; ++j)
                    acc[i][j] = mfma16(af[i], bfv[j], acc[i][j]);
        }
        __syncthreads();
    }
#pragma unroll
    for (int i = 0; i < AI; ++i) {
#pragma unroll
        for (int j = 0; j < 4; ++j) {
#pragma unroll
            for (int r = 0; r < 4; ++r) {
                int m = m0 + wr * (BM / 2) + i * 16 + g * 4 + r;
                int n = n0 + wc * 64 + j * 16 + lm;
                float v = acc[i][j][r];
                if (BF16_OUT)
                    Cb[(size_t)m * N + n] = f2bf(v);
                else
                    Cf[(size_t)m * N + n] = v + bias[n];
            }
        }
    }
}

// ---------------- K staging: XOR-pre-swizzled source -> linear LDS ----------------
__device__ inline void stage_k128t(const unsigned short* kbase, unsigned short* buf, int tid) {
    const int wave = tid >> 6, lane = tid & 63;
#pragma unroll
    for (int i = 0; i < 4; ++i) {
        int c = i * 128 + wave * 64 + lane;       // 64-row tile, 128 threads
        int row = c >> 3, j = c & 7;
        GLOAD_LDS16(kbase + (size_t)row * 3072 + ((j ^ (row & 7)) << 3),
                    buf + (i * 128 + wave * 64) * 8);
    }
}
// 128-row K tile, 256 threads
__device__ inline void stage_k256t(const unsigned short* kbase, unsigned short* buf, int tid) {
    const int wave = tid >> 6, lane = tid & 63;
#pragma unroll
    for (int i = 0; i < 4; ++i) {
        int c = i * 256 + wave * 64 + lane;
        int row = c >> 3, j = c & 7;
        GLOAD_LDS16(kbase + (size_t)row * 3072 + ((j ^ (row & 7)) << 3),
                    buf + (i * 256 + wave * 64) * 8);
    }
}

// ---------------- attn kernel 1: softmax denominator PARTIAL sums ----------------
// K-SPLIT: grid 2048 (2 K-halves x 32 q-blocks x 32 bh), 4 waves/SIMD so the
// v_exp_f32 (quarter-rate) pipe overlaps MFMA across waves. Writes raw partial
// sums to plane[khalf]; attn_write combines rv = 1/(pa+pb) (deterministic).
__global__ __launch_bounds__(128, 4)
void attn_sums(const unsigned short* __restrict__ qkv, float* __restrict__ psum_out) {
    __shared__ unsigned short kt[2 * 4096];
    const int tid = threadIdx.x, lane = tid & 63, wave = tid >> 6;
    const int l31 = lane & 31, h5 = lane >> 5, l7 = lane & 7;
    const int flat = blockIdx.x;
    const int work = (flat & 7) * 256 + (flat >> 3);
    const int khalf = work & 1;
    const int q0 = ((work >> 1) & 31) * 64;
    const int h = (work >> 6) & 15, b = work >> 10;
    const unsigned short* qkvB = qkv + (size_t)b * N_ * 3072;
    const unsigned short* kh = qkvB + 1024 + h * 64;
    const int kt0 = khalf * 16;

    const unsigned short* qrow = qkvB + (size_t)(q0 + wave * 32 + l31) * 3072 + h * 64;
    short8 aq[4];
#pragma unroll
    for (int ks = 0; ks < 4; ++ks) aq[ks] = *(const short8*)(qrow + ks * 16 + h5 * 8);

    float psum = 0.f;
    stage_k128t(kh + (size_t)kt0 * 196608, kt, tid);
    __syncthreads();

    for (int ktr = 0; ktr < 16; ++ktr) {
        const int cur = ktr & 1;
        if (ktr < 15)
            stage_k128t(kh + (size_t)(kt0 + ktr + 1) * 196608, kt + (cur ^ 1) * 4096, tid);
        const unsigned short* ktc = kt + cur * 4096;
        f32x16 s0 = {}, s1 = {};
        __builtin_amdgcn_s_setprio(1);
#pragma unroll
        for (int ks = 0; ks < 4; ++ks) {
            int ch = ((ks * 2 + h5) ^ l7) * 8;
            short8 b0 = *(const short8*)&ktc[l31 * 64 + ch];
            short8 b1 = *(const short8*)&ktc[(32 + l31) * 64 + ch];
            s0 = mfma32(b0, aq[ks], s0);
            s1 = mfma32(b1, aq[ks], s1);
        }
        __builtin_amdgcn_s_setprio(0);
#pragma unroll
        for (int r = 0; r < 16; ++r)
            psum += __expf(s0[r] * SCALE_) + __expf(s1[r] * SCALE_);
        __syncthreads();
    }
    psum += __shfl_xor(psum, 32);
    if (h5 == 0)
        psum_out[(size_t)khalf * 65536 + (size_t)(b * H_ + h) * N_ + q0 + wave * 32 + l31] = psum;
}

// ---------------- attn kernel 2: attn write + PV, KVBLK=128 (unchanged sched) ----------------
__global__ __launch_bounds__(256, 2)
void attn_write(const unsigned short* __restrict__ qkv, const float* __restrict__ psum_in,
                float* __restrict__ attn_out, unsigned short* __restrict__ o_out) {
    __shared__ unsigned short smem[32768];   // 65,536 B
    unsigned short* kt = smem;               // [2][128][64]
    unsigned short* vt = smem + 16384;       // [2][64][64] swizzled V^T
    float* pw = (float*)(smem + 24576);      // [4 waves][8 q][128]

    const int tid = threadIdx.x, lane = tid & 63, wave = tid >> 6;
    const int l31 = lane & 31, h5 = lane >> 5, l7 = lane & 7;
    const int flat = blockIdx.x;
    const int work = ((flat & 7) << 6) | (flat >> 3);
    const int q0 = (work & 15) * 128, h = (work >> 4) & 15, b = work >> 8;
    const unsigned short* qkvB = qkv + (size_t)b * N_ * 3072;
    const unsigned short* kh = qkvB + 1024 + h * 64;
    const unsigned short* vh = qkvB + 2048 + h * 64;

    const unsigned short* qrow = qkvB + (size_t)(q0 + wave * 32 + l31) * 3072 + h * 64;
    short8 aq[4];
#pragma unroll
    for (int ks = 0; ks < 4; ++ks) aq[ks] = *(const short8*)(qrow + ks * 16 + h5 * 8);

    // combine the two K-half partial sums (deterministic)
    const float* rp = psum_in + (size_t)(b * H_ + h) * N_ + q0 + wave * 32 + l31;
    const float rv = 1.0f / (rp[0] + rp[65536]);

    const int rV = (tid >> 3) * 2, cV = (tid & 7) * 8;
    short8 va, vb, vc, vd;
#define LOADV(base_) do { const unsigned short* sv = (base_) + (size_t)rV * 3072 + cV;   \
        va = *(const short8*)sv; vb = *(const short8*)(sv + 3072);                       \
        vc = *(const short8*)(sv + (size_t)64 * 3072);                                   \
        vd = *(const short8*)(sv + (size_t)65 * 3072); } while (0)
#define WRITEV() do { _Pragma("unroll") for (int j = 0; j < 8; ++j) {     \
        int d = cV + j; int w = (rV >> 1) ^ (((d >> 3) & 7) << 2);        \
        *(unsigned int*)&vt[d * 64 + 2 * w] =                             \
            (unsigned int)(unsigned short)va[j] |                         \
            ((unsigned int)(unsigned short)vb[j] << 16);                  \
        *(unsigned int*)&vt[4096 + d * 64 + 2 * w] =                      \
            (unsigned int)(unsigned short)vc[j] |                         \
            ((unsigned int)(unsigned short)vd[j] << 16); } } while (0)

    stage_k256t(kh, kt, tid);
    LOADV(vh);
    WRITEV();
    __syncthreads();

    f32x16 oa0 = {}, oa1 = {};
    float* attnB = attn_out + ((size_t)(b * H_ + h) * N_ + q0) * N_;
    float* aw = attnB + (size_t)(wave * 32) * N_;
    float* pww = pw + wave * 1024;

    for (int kti = 0; kti < 16; ++kti) {
        const int cur = kti & 1;
        if (kti > 0) {
            asm volatile("s_waitcnt vmcnt(16) lgkmcnt(0)\n\ts_barrier" ::: "memory");
            __builtin_amdgcn_sched_barrier(0);
        }
        if (kti < 15) {
            stage_k256t(kh + (size_t)(kti + 1) * 393216, kt + (cur ^ 1) * 8192, tid);
            LOADV(vh + (size_t)(kti + 1) * 393216);
        }
        const unsigned short* ktc = kt + cur * 8192;
        f32x16 s[4];
        s[0] = (f32x16){}; s[1] = (f32x16){}; s[2] = (f32x16){}; s[3] = (f32x16){};
        __builtin_amdgcn_s_setprio(1);
#pragma unroll
        for (int a = 0; a < 4; ++a)
#pragma unroll
            for (int ks = 0; ks < 4; ++ks) {
                short8 kf = *(const short8*)&ktc[(a * 32 + l31) * 64 + ((ks * 2 + h5) ^ l7) * 8];
                s[a] = mfma32(kf, aq[ks], s[a]);
            }
        __builtin_amdgcn_s_setprio(0);

#pragma unroll
        for (int a = 0; a < 4; ++a)
#pragma unroll
            for (int r = 0; r < 16; ++r)
                s[a][r] = __expf(s[a][r] * SCALE_) * rv;

#pragma unroll
        for (int bs = 0; bs < 4; ++bs) {
            if ((l31 >> 3) == bs) {
                int r7 = l31 & 7;
                float* pr = pww + r7 * 128;
#pragma unroll
                for (int a = 0; a < 4; ++a)
#pragma unroll
                    for (int j = 0; j < 4; ++j) {
                        int col = a * 32 + 8 * j + 4 * h5;
                        f32x4 pv = {s[a][4 * j], s[a][4 * j + 1], s[a][4 * j + 2], s[a][4 * j + 3]};
                        *(f32x4*)&pr[col ^ (r7 << 2)] = pv;
                    }
            }
#pragma unroll
            for (int j2 = 0; j2 < 4; ++j2) {
                int row = 8 * bs + 2 * j2 + h5;
                int r7s = row & 7;
                f32x4 vvv = *(const f32x4*)&pww[r7s * 128 + ((4 * l31) ^ (r7s << 2))];
                __builtin_nontemporal_store(vvv,
                    (f32x4*)(aw + (size_t)row * N_ + kti * 128 + 4 * l31));
            }
        }

        unsigned int pb[32];
#pragma unroll
        for (int g2 = 0; g2 < 2; ++g2) {
#pragma unroll
            for (int c4 = 0; c4 < 8; ++c4) {
                int rb = (c4 & 3) * 4;
                const f32x16& sv2 = s[2 * g2 + (c4 >> 2)];
                CVTPK(pb[16 * g2 + 2 * c4], sv2[rb], sv2[rb + 1]);
                CVTPK(pb[16 * g2 + 2 * c4 + 1], sv2[rb + 2], sv2[rb + 3]);
            }
#pragma unroll
            for (int fs = 0; fs < 4; ++fs) {
                PLSWAP(pb[16 * g2 + 4 * fs + 0], pb[16 * g2 + 4 * fs + 2]);
                PLSWAP(pb[16 * g2 + 4 * fs + 1], pb[16 * g2 + 4 * fs + 3]);
            }
        }

        __builtin_amdgcn_s_setprio(1);
#pragma unroll
        for (int g2 = 0; g2 < 2; ++g2)
#pragma unroll
            for (int ks = 0; ks < 4; ++ks) {
                short8 ap;
                {
                    u32x4 t = {pb[16 * g2 + 4 * ks], pb[16 * g2 + 4 * ks + 1],
                               pb[16 * g2 + 4 * ks + 2], pb[16 * g2 + 4 * ks + 3]};
                    ap = *(short8*)&t;
                }
                int wbase = ks * 8 + h5 * 4;
                int w0 = wbase ^ (((l31 >> 3) & 7) << 2);
                short8 bv0 = *(const short8*)&vt[g2 * 4096 + l31 * 64 + 2 * w0];
                int d1 = 32 + l31;
                int w1 = wbase ^ (((d1 >> 3) & 7) << 2);
                short8 bv1 = *(const short8*)&vt[g2 * 4096 + d1 * 64 + 2 * w1];
                oa0 = mfma32(ap, bv0, oa0);
                oa1 = mfma32(ap, bv1, oa1);
            }
        __builtin_amdgcn_s_setprio(0);

        if (kti < 15) {
            asm volatile("s_waitcnt lgkmcnt(0)\n\ts_barrier" ::: "memory");
            __builtin_amdgcn_sched_barrier(0);
            WRITEV();
        }
    }

#pragma unroll
    for (int r = 0; r < 16; ++r) {
        int qrw = q0 + wave * 32 + 4 * h5 + (r & 3) + 8 * (r >> 2);
        size_t ob = (size_t)(b * N_ + qrw) * C_ + h * 64 + l31;
        o_out[ob] = f2bf(oa0[r]);
        o_out[ob + 32] = f2bf(oa1[r]);
    }
#undef WRITEV
#undef LOADV
}

extern "C" void kernel_launch(void* const* d_in, const int* in_sizes, int n_in,
                              void* d_out, int out_size, void* d_ws, size_t ws_size,
                              hipStream_t stream) {
    (void)in_sizes; (void)n_in; (void)out_size; (void)ws_size;
    const float* x      = (const float*)d_in[0];
    const float* w_qkv  = (const float*)d_in[1];
    const float* w_proj = (const float*)d_in[2];
    const float* b_proj = (const float*)d_in[3];

    float* out  = (float*)d_out;                       // [2,2048,1024] fp32
    float* attn = out + (size_t)B_ * N_ * C_;          // [2,16,2048,2048] fp32

    unsigned short* x_b     = (unsigned short*)d_ws;            // 4096x1024 (dead after qkv GEMM)
    unsigned short* wqkv_b  = x_b + (size_t)4096 * 1024;        // 3072x1024
    unsigned short* wproj_b = wqkv_b + (size_t)3072 * 1024;     // 1024x1024
    unsigned short* qkv_b   = wproj_b + (size_t)1024 * 1024;    // 4096x3072
    unsigned short* o_b     = qkv_b + (size_t)4096 * 3072;      // 4096x1024
    float* psums = (float*)x_b;                                 // 2 planes of 64K floats

    cvt_all<<<8192, 256, 0, stream>>>(x, w_qkv, w_proj, x_b, wqkv_b, wproj_b);

    // ATTRIBUTION: qkv GEMM launched twice (identical, deterministic).
    // T(qkv) = dur(R11) - dur(R10) + Δsums. Revert to single launch next round.
    gemm_bt<1, 128><<<768, 256, 0, stream>>>(
        x_b, wqkv_b, qkv_b, nullptr, nullptr, 4096, 3072, 1024, 2, 12);
    gemm_bt<1, 128><<<768, 256, 0, stream>>>(
        x_b, wqkv_b, qkv_b, nullptr, nullptr, 4096, 3072, 1024, 2, 12);

    attn_sums<<<2048, 128, 0, stream>>>(qkv_b, psums);
    attn_write<<<512, 256, 0, stream>>>(qkv_b, psums, attn, o_b);

    gemm_bt<0, 64><<<512, 256, 0, stream>>>(
        o_b, wproj_b, nullptr, out, b_proj, 4096, 1024, 1024, 1, 8);
}

// Round 12
// 210.364 us; speedup vs baseline: 1.1550x; 1.1550x over previous
//
#include <hip/hip_runtime.h>

typedef __attribute__((ext_vector_type(8))) short short8;
typedef __attribute__((ext_vector_type(4))) float f32x4;
typedef __attribute__((ext_vector_type(16))) float f32x16;
typedef __attribute__((ext_vector_type(4))) unsigned int u32x4;

#define B_ 2
#define N_ 2048
#define C_ 1024
#define H_ 16
#define SCALE_ 0.03125f

__device__ inline unsigned short f2bf(float f) {
    unsigned int u = __float_as_uint(f);
    return (unsigned short)((u + 0x7fffu + ((u >> 16) & 1u)) >> 16);
}

__device__ inline f32x4 mfma16(short8 a, short8 b, f32x4 c) {
    return __builtin_amdgcn_mfma_f32_16x16x32_bf16(a, b, c, 0, 0, 0);
}
__device__ inline f32x16 mfma32(short8 a, short8 b, f32x16 c) {
    return __builtin_amdgcn_mfma_f32_32x32x16_bf16(a, b, c, 0, 0, 0);
}

#define GLOAD_LDS16(g, l) __builtin_amdgcn_global_load_lds( \
    (const __attribute__((address_space(1))) void*)(g),     \
    (__attribute__((address_space(3))) void*)(l), 16, 0, 0)

#define CVTPK(d, x, y) asm("v_cvt_pk_bf16_f32 %0, %1, %2" : "=v"(d) : "v"(x), "v"(y))
#define PLSWAP(a, b) asm volatile("v_permlane32_swap_b32 %0, %1" : "+v"(a), "+v"(b))

// ---------------- fused fp32 -> bf16 convert ----------------
__global__ void cvt_all(const float* __restrict__ x, const float* __restrict__ wq,
                        const float* __restrict__ wp, unsigned short* __restrict__ xb,
                        unsigned short* __restrict__ wqb, unsigned short* __restrict__ wpb) {
    int i = blockIdx.x * blockDim.x + threadIdx.x;
    const int n1 = 4096 * 1024 / 4, n2 = 3072 * 1024 / 4;
    const float* src; unsigned short* dst; int j;
    if (i < n1)            { src = x;  dst = xb;  j = i; }
    else if (i < n1 + n2)  { src = wq; dst = wqb; j = i - n1; }
    else                   { src = wp; dst = wpb; j = i - n1 - n2; }
    float4 v = *(const float4*)(src + (size_t)j * 4);
    ushort4 o;
    o.x = f2bf(v.x); o.y = f2bf(v.y); o.z = f2bf(v.z); o.w = f2bf(v.w);
    *(ushort4*)(dst + (size_t)j * 4) = o;
}

// ---------------- bf16 B^T GEMM, BMx128 tile, BK=64 (unchanged) ----------------
template<int BF16_OUT, int BM>
__global__ __launch_bounds__(256, 3)
void gemm_bt(const unsigned short* __restrict__ A, const unsigned short* __restrict__ Bm,
             unsigned short* __restrict__ Cb, float* __restrict__ Cf,
             const float* __restrict__ bias, int M, int N, int K,
             int xcd_cols, int bxr) {
    constexpr int AI = BM / 32;
    __shared__ unsigned short lA[BM * 64];
    __shared__ unsigned short lB[128 * 64];
    const int tid = threadIdx.x;
    const int lane = tid & 63, wave = tid >> 6;
    const int lm = lane & 15, g = lane >> 4;
    const int flat = blockIdx.x, per = gridDim.x >> 3;
    const int xcd = flat & 7, fl = flat >> 3;
    const int rpr = per / bxr;
    const int by = (xcd / xcd_cols) * rpr + fl / bxr;
    const int bx = (xcd % xcd_cols) * bxr + fl % bxr;
    const int m0 = by * BM, n0 = bx * 128;
    const int wr = wave >> 1, wc = wave & 1;

    f32x4 acc[AI][4];
    f32x4 zero = {0.f, 0.f, 0.f, 0.f};
#pragma unroll
    for (int i = 0; i < AI; ++i)
#pragma unroll
        for (int j = 0; j < 4; ++j) acc[i][j] = zero;

    const int sRow = lane >> 3;
    const int sCol = (lane & 7) * 8;

    for (int k0 = 0; k0 < K; k0 += 64) {
#pragma unroll
        for (int t = 0; t < AI; ++t) {
            int inst = wave * AI + t;
            int r = inst * 8 + sRow;
            GLOAD_LDS16(A + (size_t)(m0 + r) * K + k0 + sCol, lA + inst * 512);
        }
#pragma unroll
        for (int t = 0; t < 4; ++t) {
            int inst = wave * 4 + t;
            int r = inst * 8 + sRow;
            GLOAD_LDS16(Bm + (size_t)(n0 + r) * K + k0 + sCol, lB + inst * 512);
        }
        __syncthreads();
#pragma unroll
        for (int kk = 0; kk < 2; ++kk) {
            short8 af[AI], bfv[4];
#pragma unroll
            for (int i = 0; i < AI; ++i)
                af[i] = *(const short8*)&lA[(wr * (BM / 2) + i * 16 + lm) * 64 + kk * 32 + g * 8];
#pragma unroll
            for (int j = 0; j < 4; ++j)
                bfv[j] = *(const short8*)&lB[(wc * 64 + j * 16 + lm) * 64 + kk * 32 + g * 8];
#pragma unroll
            for (int i = 0; i < AI; ++i)
#pragma unroll
                for (int j = 0; j < 4; ++j)
                    acc[i][j] = mfma16(af[i], bfv[j], acc[i][j]);
        }
        __syncthreads();
    }
#pragma unroll
    for (int i = 0; i < AI; ++i) {
#pragma unroll
        for (int j = 0; j < 4; ++j) {
#pragma unroll
            for (int r = 0; r < 4; ++r) {
                int m = m0 + wr * (BM / 2) + i * 16 + g * 4 + r;
                int n = n0 + wc * 64 + j * 16 + lm;
                float v = acc[i][j][r];
                if (BF16_OUT)
                    Cb[(size_t)m * N + n] = f2bf(v);
                else
                    Cf[(size_t)m * N + n] = v + bias[n];
            }
        }
    }
}

// ---------------- K staging: XOR-pre-swizzled source -> linear LDS ----------------
__device__ inline void stage_k128t(const unsigned short* kbase, unsigned short* buf, int tid) {
    const int wave = tid >> 6, lane = tid & 63;
#pragma unroll
    for (int i = 0; i < 4; ++i) {
        int c = i * 128 + wave * 64 + lane;       // 64-row tile, 128 threads
        int row = c >> 3, j = c & 7;
        GLOAD_LDS16(kbase + (size_t)row * 3072 + ((j ^ (row & 7)) << 3),
                    buf + (i * 128 + wave * 64) * 8);
    }
}
// 128-row K tile, 256 threads
__device__ inline void stage_k256t(const unsigned short* kbase, unsigned short* buf, int tid) {
    const int wave = tid >> 6, lane = tid & 63;
#pragma unroll
    for (int i = 0; i < 4; ++i) {
        int c = i * 256 + wave * 64 + lane;
        int row = c >> 3, j = c & 7;
        GLOAD_LDS16(kbase + (size_t)row * 3072 + ((j ^ (row & 7)) << 3),
                    buf + (i * 256 + wave * 64) * 8);
    }
}

// ---------------- attn kernel 1: softmax denominator PARTIAL sums (K-split) ----------------
__global__ __launch_bounds__(128, 4)
void attn_sums(const unsigned short* __restrict__ qkv, float* __restrict__ psum_out) {
    __shared__ unsigned short kt[2 * 4096];
    const int tid = threadIdx.x, lane = tid & 63, wave = tid >> 6;
    const int l31 = lane & 31, h5 = lane >> 5, l7 = lane & 7;
    const int flat = blockIdx.x;
    const int work = (flat & 7) * 256 + (flat >> 3);
    const int khalf = work & 1;
    const int q0 = ((work >> 1) & 31) * 64;
    const int h = (work >> 6) & 15, b = work >> 10;
    const unsigned short* qkvB = qkv + (size_t)b * N_ * 3072;
    const unsigned short* kh = qkvB + 1024 + h * 64;
    const int kt0 = khalf * 16;

    const unsigned short* qrow = qkvB + (size_t)(q0 + wave * 32 + l31) * 3072 + h * 64;
    short8 aq[4];
#pragma unroll
    for (int ks = 0; ks < 4; ++ks) aq[ks] = *(const short8*)(qrow + ks * 16 + h5 * 8);

    float psum = 0.f;
    stage_k128t(kh + (size_t)kt0 * 196608, kt, tid);
    __syncthreads();

    for (int ktr = 0; ktr < 16; ++ktr) {
        const int cur = ktr & 1;
        if (ktr < 15)
            stage_k128t(kh + (size_t)(kt0 + ktr + 1) * 196608, kt + (cur ^ 1) * 4096, tid);
        const unsigned short* ktc = kt + cur * 4096;
        f32x16 s0 = {}, s1 = {};
        __builtin_amdgcn_s_setprio(1);
#pragma unroll
        for (int ks = 0; ks < 4; ++ks) {
            int ch = ((ks * 2 + h5) ^ l7) * 8;
            short8 b0 = *(const short8*)&ktc[l31 * 64 + ch];
            short8 b1 = *(const short8*)&ktc[(32 + l31) * 64 + ch];
            s0 = mfma32(b0, aq[ks], s0);
            s1 = mfma32(b1, aq[ks], s1);
        }
        __builtin_amdgcn_s_setprio(0);
#pragma unroll
        for (int r = 0; r < 16; ++r)
            psum += __expf(s0[r] * SCALE_) + __expf(s1[r] * SCALE_);
        __syncthreads();
    }
    psum += __shfl_xor(psum, 32);
    if (h5 == 0)
        psum_out[(size_t)khalf * 65536 + (size_t)(b * H_ + h) * N_ + q0 + wave * 32 + l31] = psum;
}

// ---------------- attn kernel 2: attn write + PV, KVBLK=128 (unchanged) ----------------
__global__ __launch_bounds__(256, 2)
void attn_write(const unsigned short* __restrict__ qkv, const float* __restrict__ psum_in,
                float* __restrict__ attn_out, unsigned short* __restrict__ o_out) {
    __shared__ unsigned short smem[32768];   // 65,536 B
    unsigned short* kt = smem;               // [2][128][64]
    unsigned short* vt = smem + 16384;       // [2][64][64] swizzled V^T
    float* pw = (float*)(smem + 24576);      // [4 waves][8 q][128]

    const int tid = threadIdx.x, lane = tid & 63, wave = tid >> 6;
    const int l31 = lane & 31, h5 = lane >> 5, l7 = lane & 7;
    const int flat = blockIdx.x;
    const int work = ((flat & 7) << 6) | (flat >> 3);
    const int q0 = (work & 15) * 128, h = (work >> 4) & 15, b = work >> 8;
    const unsigned short* qkvB = qkv + (size_t)b * N_ * 3072;
    const unsigned short* kh = qkvB + 1024 + h * 64;
    const unsigned short* vh = qkvB + 2048 + h * 64;

    const unsigned short* qrow = qkvB + (size_t)(q0 + wave * 32 + l31) * 3072 + h * 64;
    short8 aq[4];
#pragma unroll
    for (int ks = 0; ks < 4; ++ks) aq[ks] = *(const short8*)(qrow + ks * 16 + h5 * 8);

    const float* rp = psum_in + (size_t)(b * H_ + h) * N_ + q0 + wave * 32 + l31;
    const float rv = 1.0f / (rp[0] + rp[65536]);

    const int rV = (tid >> 3) * 2, cV = (tid & 7) * 8;
    short8 va, vb, vc, vd;
#define LOADV(base_) do { const unsigned short* sv = (base_) + (size_t)rV * 3072 + cV;   \
        va = *(const short8*)sv; vb = *(const short8*)(sv + 3072);                       \
        vc = *(const short8*)(sv + (size_t)64 * 3072);                                   \
        vd = *(const short8*)(sv + (size_t)65 * 3072); } while (0)
#define WRITEV() do { _Pragma("unroll") for (int j = 0; j < 8; ++j) {     \
        int d = cV + j; int w = (rV >> 1) ^ (((d >> 3) & 7) << 2);        \
        *(unsigned int*)&vt[d * 64 + 2 * w] =                             \
            (unsigned int)(unsigned short)va[j] |                         \
            ((unsigned int)(unsigned short)vb[j] << 16);                  \
        *(unsigned int*)&vt[4096 + d * 64 + 2 * w] =                      \
            (unsigned int)(unsigned short)vc[j] |                         \
            ((unsigned int)(unsigned short)vd[j] << 16); } } while (0)

    stage_k256t(kh, kt, tid);
    LOADV(vh);
    WRITEV();
    __syncthreads();

    f32x16 oa0 = {}, oa1 = {};
    float* attnB = attn_out + ((size_t)(b * H_ + h) * N_ + q0) * N_;
    float* aw = attnB + (size_t)(wave * 32) * N_;
    float* pww = pw + wave * 1024;

    for (int kti = 0; kti < 16; ++kti) {
        const int cur = kti & 1;
        if (kti > 0) {
            asm volatile("s_waitcnt vmcnt(16) lgkmcnt(0)\n\ts_barrier" ::: "memory");
            __builtin_amdgcn_sched_barrier(0);
        }
        if (kti < 15) {
            stage_k256t(kh + (size_t)(kti + 1) * 393216, kt + (cur ^ 1) * 8192, tid);
            LOADV(vh + (size_t)(kti + 1) * 393216);
        }
        const unsigned short* ktc = kt + cur * 8192;
        f32x16 s[4];
        s[0] = (f32x16){}; s[1] = (f32x16){}; s[2] = (f32x16){}; s[3] = (f32x16){};
        __builtin_amdgcn_s_setprio(1);
#pragma unroll
        for (int a = 0; a < 4; ++a)
#pragma unroll
            for (int ks = 0; ks < 4; ++ks) {
                short8 kf = *(const short8*)&ktc[(a * 32 + l31) * 64 + ((ks * 2 + h5) ^ l7) * 8];
                s[a] = mfma32(kf, aq[ks], s[a]);
            }
        __builtin_amdgcn_s_setprio(0);

#pragma unroll
        for (int a = 0; a < 4; ++a)
#pragma unroll
            for (int r = 0; r < 16; ++r)
                s[a][r] = __expf(s[a][r] * SCALE_) * rv;

#pragma unroll
        for (int bs = 0; bs < 4; ++bs) {
            if ((l31 >> 3) == bs) {
                int r7 = l31 & 7;
                float* pr = pww + r7 * 128;
#pragma unroll
                for (int a = 0; a < 4; ++a)
#pragma unroll
                    for (int j = 0; j < 4; ++j) {
                        int col = a * 32 + 8 * j + 4 * h5;
                        f32x4 pv = {s[a][4 * j], s[a][4 * j + 1], s[a][4 * j + 2], s[a][4 * j + 3]};
                        *(f32x4*)&pr[col ^ (r7 << 2)] = pv;
                    }
            }
#pragma unroll
            for (int j2 = 0; j2 < 4; ++j2) {
                int row = 8 * bs + 2 * j2 + h5;
                int r7s = row & 7;
                f32x4 vvv = *(const f32x4*)&pww[r7s * 128 + ((4 * l31) ^ (r7s << 2))];
                __builtin_nontemporal_store(vvv,
                    (f32x4*)(aw + (size_t)row * N_ + kti * 128 + 4 * l31));
            }
        }

        unsigned int pb[32];
#pragma unroll
        for (int g2 = 0; g2 < 2; ++g2) {
#pragma unroll
            for (int c4 = 0; c4 < 8; ++c4) {
                int rb = (c4 & 3) * 4;
                const f32x16& sv2 = s[2 * g2 + (c4 >> 2)];
                CVTPK(pb[16 * g2 + 2 * c4], sv2[rb], sv2[rb + 1]);
                CVTPK(pb[16 * g2 + 2 * c4 + 1], sv2[rb + 2], sv2[rb + 3]);
            }
#pragma unroll
            for (int fs = 0; fs < 4; ++fs) {
                PLSWAP(pb[16 * g2 + 4 * fs + 0], pb[16 * g2 + 4 * fs + 2]);
                PLSWAP(pb[16 * g2 + 4 * fs + 1], pb[16 * g2 + 4 * fs + 3]);
            }
        }

        __builtin_amdgcn_s_setprio(1);
#pragma unroll
        for (int g2 = 0; g2 < 2; ++g2)
#pragma unroll
            for (int ks = 0; ks < 4; ++ks) {
                short8 ap;
                {
                    u32x4 t = {pb[16 * g2 + 4 * ks], pb[16 * g2 + 4 * ks + 1],
                               pb[16 * g2 + 4 * ks + 2], pb[16 * g2 + 4 * ks + 3]};
                    ap = *(short8*)&t;
                }
                int wbase = ks * 8 + h5 * 4;
                int w0 = wbase ^ (((l31 >> 3) & 7) << 2);
                short8 bv0 = *(const short8*)&vt[g2 * 4096 + l31 * 64 + 2 * w0];
                int d1 = 32 + l31;
                int w1 = wbase ^ (((d1 >> 3) & 7) << 2);
                short8 bv1 = *(const short8*)&vt[g2 * 4096 + d1 * 64 + 2 * w1];
                oa0 = mfma32(ap, bv0, oa0);
                oa1 = mfma32(ap, bv1, oa1);
            }
        __builtin_amdgcn_s_setprio(0);

        if (kti < 15) {
            asm volatile("s_waitcnt lgkmcnt(0)\n\ts_barrier" ::: "memory");
            __builtin_amdgcn_sched_barrier(0);
            WRITEV();
        }
    }

#pragma unroll
    for (int r = 0; r < 16; ++r) {
        int qrw = q0 + wave * 32 + 4 * h5 + (r & 3) + 8 * (r >> 2);
        size_t ob = (size_t)(b * N_ + qrw) * C_ + h * 64 + l31;
        o_out[ob] = f2bf(oa0[r]);
        o_out[ob + 32] = f2bf(oa1[r]);
    }
#undef WRITEV
#undef LOADV
}

extern "C" void kernel_launch(void* const* d_in, const int* in_sizes, int n_in,
                              void* d_out, int out_size, void* d_ws, size_t ws_size,
                              hipStream_t stream) {
    (void)in_sizes; (void)n_in; (void)out_size; (void)ws_size;
    const float* x      = (const float*)d_in[0];
    const float* w_qkv  = (const float*)d_in[1];
    const float* w_proj = (const float*)d_in[2];
    const float* b_proj = (const float*)d_in[3];

    float* out  = (float*)d_out;                       // [2,2048,1024] fp32
    float* attn = out + (size_t)B_ * N_ * C_;          // [2,16,2048,2048] fp32

    unsigned short* x_b     = (unsigned short*)d_ws;            // 4096x1024 (dead after qkv GEMM)
    unsigned short* wqkv_b  = x_b + (size_t)4096 * 1024;        // 3072x1024
    unsigned short* wproj_b = wqkv_b + (size_t)3072 * 1024;     // 1024x1024
    unsigned short* qkv_b   = wproj_b + (size_t)1024 * 1024;    // 4096x3072
    unsigned short* o_b     = qkv_b + (size_t)4096 * 3072;      // 4096x1024
    float* psums = (float*)x_b;                                 // 2 planes of 64K floats

    cvt_all<<<8192, 256, 0, stream>>>(x, w_qkv, w_proj, x_b, wqkv_b, wproj_b);

    // single qkv launch (attribution dup removed):
    // T(qkv) = dur(R11) - dur(R12); Δsums(K-split) = dur(R12) - dur(R10).
    gemm_bt<1, 128><<<768, 256, 0, stream>>>(
        x_b, wqkv_b, qkv_b, nullptr, nullptr, 4096, 3072, 1024, 2, 12);

    attn_sums<<<2048, 128, 0, stream>>>(qkv_b, psums);
    attn_write<<<512, 256, 0, stream>>>(qkv_b, psums, attn, o_b);

    gemm_bt<0, 64><<<512, 256, 0, stream>>>(
        o_b, wproj_b, nullptr, out, b_proj, 4096, 1024, 1024, 1, 8);
}